// Round 1
// baseline (125.726 us; speedup 1.0000x reference)
//
#include <hip/hip_runtime.h>
#include <math.h>

// Hit-miss transform: out[i][j] = min_{di,dj}(x[i+di][j+dj] - Khit[di][dj])
//                               - max_{di,dj}(x[i+di][j+dj] - Kmiss[di][dj])
// H=W=4096 fp32 input, 5x5 kernels, output 4092x4092 fp32.
//
// R4: grid-packing fix. Counters showed no saturated pipe (VALU 52%, HBM 28%)
// with Occupancy 60% — the 2728-block grid ran as 2 resident rounds of the
// 2048-block co-resident set (8 blocks/CU x 256 CU), the second only 33% full.
// RPT 6 -> 4 gives grid = 4 x 1023 = 4092 blocks = 1.998 exact rounds
// (round 2 is 99.8% full). Compute structure unchanged (R3's min3/max3 fold +
// 6-deep cyclic register row window is RPT-generic; max prefetch row
// r0+7 <= 4095 stays in bounds).

constexpr int KS  = 5;
constexpr int WW  = 4096;
constexpr int HO  = 4092;
constexpr int WO  = 4092;
constexpr int CG  = WO / 4;   // 1023 column groups
constexpr int RPT = 4;        // output rows per thread (4092 = 4*1023)

__device__ __forceinline__ float min3f(float a, float b, float c) {
    float d;
    asm("v_min3_f32 %0, %1, %2, %3" : "=v"(d) : "v"(a), "v"(b), "v"(c));
    return d;
}
__device__ __forceinline__ float max3f(float a, float b, float c) {
    float d;
    asm("v_max3_f32 %0, %1, %2, %3" : "=v"(d) : "v"(a), "v"(b), "v"(c));
    return d;
}

__global__ __launch_bounds__(256) void hitmiss_kernel(
    const float* __restrict__ x,
    const float* __restrict__ kh,
    const float* __restrict__ km,
    float* __restrict__ out)
{
    const int cg = blockIdx.x * blockDim.x + threadIdx.x;  // column group
    if (cg >= CG) return;
    const int j0 = cg * 4;
    const int r0 = blockIdx.y * RPT;

    // Kernel weights: uniform addresses -> scalar loads into SGPRs.
    float wh[KS * KS], wm[KS * KS];
#pragma unroll
    for (int i = 0; i < KS * KS; ++i) {
        wh[i] = kh[i];
        wm[i] = km[i];
    }

    const float* base = x + (size_t)r0 * WW + j0;

    // 6-deep cyclic window of input rows; buf[i % 6] holds input row i.
    float buf[6][8];

#pragma unroll
    for (int r = 0; r < 5; ++r) {
        float4 a = *reinterpret_cast<const float4*>(base + (size_t)r * WW);
        float4 b = *reinterpret_cast<const float4*>(base + (size_t)r * WW + 4);
        buf[r][0] = a.x; buf[r][1] = a.y; buf[r][2] = a.z; buf[r][3] = a.w;
        buf[r][4] = b.x; buf[r][5] = b.y; buf[r][6] = b.z; buf[r][7] = b.w;
    }

#pragma unroll
    for (int r = 0; r < RPT; ++r) {
        // Prefetch input row r+5 into the slot holding (dead) row r-1.
        // Issued a full output row of compute before first use.
        if (r < RPT - 1) {
            const int slot = (r + 5) % 6;
            float4 a = *reinterpret_cast<const float4*>(base + (size_t)(r + 5) * WW);
            float4 b = *reinterpret_cast<const float4*>(base + (size_t)(r + 5) * WW + 4);
            buf[slot][0] = a.x; buf[slot][1] = a.y; buf[slot][2] = a.z; buf[slot][3] = a.w;
            buf[slot][4] = b.x; buf[slot][5] = b.y; buf[slot][6] = b.z; buf[slot][7] = b.w;
        }

        float mnA[4], mnP[4], mxA[4], mxP[4];

#pragma unroll
        for (int di = 0; di < KS; ++di) {
            const int br = (r + di) % 6;   // static after unroll
#pragma unroll
            for (int dj = 0; dj < KS; ++dj) {
                const int k = di * KS + dj;
                const float h = wh[k];
                const float m = wm[k];
#pragma unroll
                for (int p = 0; p < 4; ++p) {
                    const float v  = buf[br][dj + p];
                    const float th = v - h;
                    const float tm = v - m;
                    if (k == 0) {
                        mnA[p] = th; mxA[p] = tm;
                    } else if (k & 1) {
                        mnP[p] = th; mxP[p] = tm;
                    } else {
                        // folds terms (k-1, k): 12 min3 + 12 max3 per pixel
                        mnA[p] = min3f(mnA[p], mnP[p], th);
                        mxA[p] = max3f(mxA[p], mxP[p], tm);
                    }
                }
            }
        }

        float4 o;
        o.x = mnA[0] - mxA[0];
        o.y = mnA[1] - mxA[1];
        o.z = mnA[2] - mxA[2];
        o.w = mnA[3] - mxA[3];
        *reinterpret_cast<float4*>(out + (size_t)(r0 + r) * WO + j0) = o;
    }
}

extern "C" void kernel_launch(void* const* d_in, const int* in_sizes, int n_in,
                              void* d_out, int out_size, void* d_ws, size_t ws_size,
                              hipStream_t stream) {
    const float* x  = (const float*)d_in[0];
    const float* kh = (const float*)d_in[1];
    const float* km = (const float*)d_in[2];
    float* out = (float*)d_out;

    dim3 block(256, 1, 1);
    dim3 grid((CG + 255) / 256, HO / RPT, 1);  // 4 x 1023 = 4092 blocks ~= 2 x 2048 resident
    hipLaunchKernelGGL(hitmiss_kernel, grid, block, 0, stream, x, kh, km, out);
}